// Round 1
// baseline (1541.235 us; speedup 1.0000x reference)
//
#include <hip/hip_runtime.h>

// out[i*2+0] = vertex_attr[i*2+0]
// out[i*2+1] = vertex_attr[i*2+0] * segment_sum(edge_attr, dst)[i]

__global__ void zero_f32(float* __restrict__ p, int n) {
    int i = blockIdx.x * blockDim.x + threadIdx.x;
    int stride = gridDim.x * blockDim.x;
    for (; i < n; i += stride) p[i] = 0.0f;
}

__global__ void scatter_add_edges(const int* __restrict__ dst,
                                  const float* __restrict__ edge_attr,
                                  float* __restrict__ cbar,
                                  int n_edges4) {
    int i = blockIdx.x * blockDim.x + threadIdx.x;
    int stride = gridDim.x * blockDim.x;
    const int4* __restrict__ d4 = (const int4*)dst;
    const float4* __restrict__ w4 = (const float4*)edge_attr;
    for (; i < n_edges4; i += stride) {
        int4 d = d4[i];
        float4 w = w4[i];
        atomicAdd(&cbar[d.x], w.x);
        atomicAdd(&cbar[d.y], w.y);
        atomicAdd(&cbar[d.z], w.z);
        atomicAdd(&cbar[d.w], w.w);
    }
}

__global__ void scatter_add_tail(const int* __restrict__ dst,
                                 const float* __restrict__ edge_attr,
                                 float* __restrict__ cbar,
                                 int start, int n_edges) {
    int i = start + blockIdx.x * blockDim.x + threadIdx.x;
    if (i < n_edges) atomicAdd(&cbar[dst[i]], edge_attr[i]);
}

__global__ void finalize_out(const float* __restrict__ vertex_attr,
                             const float* __restrict__ cbar,
                             float* __restrict__ out,
                             int n_vertices) {
    int i = blockIdx.x * blockDim.x + threadIdx.x;
    int stride = gridDim.x * blockDim.x;
    for (; i < n_vertices; i += stride) {
        float b = vertex_attr[2 * i];   // column 0
        float2 o;
        o.x = b;
        o.y = b * cbar[i];
        ((float2*)out)[i] = o;
    }
}

extern "C" void kernel_launch(void* const* d_in, const int* in_sizes, int n_in,
                              void* d_out, int out_size, void* d_ws, size_t ws_size,
                              hipStream_t stream) {
    const float* vertex_attr = (const float*)d_in[0];   // (n_v, 2) f32
    const int*   edgeij      = (const int*)d_in[1];     // (2, n_e) int32
    const float* edge_attr   = (const float*)d_in[2];   // (n_e, 1) f32
    // d_in[3] = g (unused), d_in[4] = batch (unused)

    const int n_vertices = in_sizes[0] / 2;
    const int n_edges    = in_sizes[2];
    const int* dst = edgeij + n_edges;  // row 1 of (2, n_e)

    float* cbar = (float*)d_ws;  // n_vertices floats of scratch

    // 1) zero the accumulator every launch (ws is poisoned, not re-zeroed)
    hipMemsetAsync(cbar, 0, (size_t)n_vertices * sizeof(float), stream);

    // 2) scatter-add, 4 edges per thread per iteration
    const int n_e4 = n_edges >> 2;
    {
        int threads = 256;
        int blocks = (n_e4 + threads - 1) / threads;
        if (blocks > 2048) blocks = 2048;
        scatter_add_edges<<<blocks, threads, 0, stream>>>(dst, edge_attr, cbar, n_e4);
    }
    const int tail_start = n_e4 << 2;
    if (tail_start < n_edges) {
        int threads = 256;
        int blocks = (n_edges - tail_start + threads - 1) / threads;
        scatter_add_tail<<<blocks, threads, 0, stream>>>(dst, edge_attr, cbar, tail_start, n_edges);
    }

    // 3) finalize: out[i] = {b, b*cbar[i]}
    {
        int threads = 256;
        int blocks = (n_vertices + threads - 1) / threads;
        if (blocks > 2048) blocks = 2048;
        finalize_out<<<blocks, threads, 0, stream>>>(vertex_attr, cbar, d_out ? (float*)d_out : nullptr, n_vertices);
    }
}